// Round 2
// baseline (1158.974 us; speedup 1.0000x reference)
//
#include <hip/hip_runtime.h>
#include <hip/hip_bf16.h>

typedef short s16x8 __attribute__((ext_vector_type(8)));
typedef float f32x4 __attribute__((ext_vector_type(4)));

constexpr int M_ = 16384;   // 8 * 2048
constexpr int N_ = 4096;    // d_out
constexpr int K_ = 4096;    // d_in
constexpr int BM = 128, BN = 128, BK = 32;

// ---------------------------------------------------------------------------
// Quantize fp32 -> integer-valued bf16 (q = rint(clip(x,-c,c)/(c/127)))
// q in [-127,127] is exactly representable in bf16.
// ---------------------------------------------------------------------------
__global__ __launch_bounds__(256) void quant_to_bf16(
    const float* __restrict__ in, ushort* __restrict__ out,
    const float* __restrict__ clip_max, int cm_idx, int n8)
{
    const float c = clip_max[cm_idx];
    const float scale = c / 127.0f;           // matches reference scale math
    int i = blockIdx.x * blockDim.x + threadIdx.x;
    const int stride = gridDim.x * blockDim.x;
    for (; i < n8; i += stride) {
        float4 v0 = ((const float4*)in)[2 * i];
        float4 v1 = ((const float4*)in)[2 * i + 1];
        float t[8] = {v0.x, v0.y, v0.z, v0.w, v1.x, v1.y, v1.z, v1.w};
        union { s16x8 v; __hip_bfloat16 h[8]; } u;
        #pragma unroll
        for (int j = 0; j < 8; ++j) {
            float xc = fminf(fmaxf(t[j], -c), c);
            float q  = rintf(xc / scale);     // round-half-even == jnp.round
            u.h[j] = __float2bfloat16(q);     // exact (|q| <= 127)
        }
        ((s16x8*)out)[i] = u.v;
    }
}

// ---------------------------------------------------------------------------
// bf16 GEMM, both operands K-major ("B^T" layout):
//   C[m][n] = (sum_k A[m][k]*B[n][k]) * s + bias[n]
// m97 structure: 128x128 tile, BK=32, 4 waves (2x2), 16x16x32 MFMA,
// global_load_lds width=16, single-buffered LDS, 2 barriers / K-step.
// ---------------------------------------------------------------------------
__global__ __launch_bounds__(256) void gemm_qbf16(
    const ushort* __restrict__ A, const ushort* __restrict__ B,
    const float* __restrict__ bias, const float* __restrict__ clip_max,
    float* __restrict__ C)
{
    __shared__ __align__(16) ushort Alds[BM * BK];   // 8 KiB
    __shared__ __align__(16) ushort Blds[BN * BK];   // 8 KiB

    const int tid = threadIdx.x;

    // XCD-aware bijective swizzle (gridDim.x = 4096, divisible by 8)
    const int nwg = gridDim.x;
    const int cpx = nwg >> 3;
    const int bid = blockIdx.x;
    const int swz = (bid & 7) * cpx + (bid >> 3);
    const int nt  = swz & (N_ / BN - 1);   // 32 n-tiles, fastest-varying
    const int mt  = swz / (N_ / BN);
    const int brow = mt * BM;
    const int bcol = nt * BN;

    const int wave = tid >> 6;
    const int lane = tid & 63;
    const int wm = wave >> 1;          // 0..1  (64-row half)
    const int wn = wave & 1;           // 0..1  (64-col half)
    const int lr = lane & 15;          // fragment row (A) / col-row (B)
    const int lk = lane >> 4;          // 0..3  -> k offset 8*lk

    f32x4 acc[4][4] = {};

    for (int kt = 0; kt < K_ / BK; ++kt) {
        const int koff = kt * BK;
        // ---- stage A/B tiles: 2 x 4096B each via global_load_lds width=16
        #pragma unroll
        for (int i = 0; i < 2; ++i) {
            const int l    = i * 2048 + tid * 8;  // bf16 element index in tile
            const int r    = l >> 5;              // row in tile
            const int ccol = l & 31;              // k within tile (mult of 8)
            __builtin_amdgcn_global_load_lds(
                (const __attribute__((address_space(1))) void*)
                    (A + (size_t)(brow + r) * K_ + koff + ccol),
                (__attribute__((address_space(3))) void*)(&Alds[l]),
                16, 0, 0);
            __builtin_amdgcn_global_load_lds(
                (const __attribute__((address_space(1))) void*)
                    (B + (size_t)(bcol + r) * K_ + koff + ccol),
                (__attribute__((address_space(3))) void*)(&Blds[l]),
                16, 0, 0);
        }
        __syncthreads();   // drains vmcnt -> staged data visible

        // ---- LDS -> fragments (contiguous 16B reads)
        s16x8 af[4], bfr[4];
        #pragma unroll
        for (int mi = 0; mi < 4; ++mi)
            af[mi] = *(const s16x8*)&Alds[(wm * 64 + mi * 16 + lr) * BK + 8 * lk];
        #pragma unroll
        for (int ni = 0; ni < 4; ++ni)
            bfr[ni] = *(const s16x8*)&Blds[(wn * 64 + ni * 16 + lr) * BK + 8 * lk];

        // ---- 16 MFMAs, acc += A*B
        #pragma unroll
        for (int mi = 0; mi < 4; ++mi)
            #pragma unroll
            for (int ni = 0; ni < 4; ++ni)
                acc[mi][ni] = __builtin_amdgcn_mfma_f32_16x16x32_bf16(
                    af[mi], bfr[ni], acc[mi][ni], 0, 0, 0);
        __syncthreads();   // protect LDS before next-stage overwrite
    }

    // ---- epilogue: scale + bias
    const float s = (clip_max[0] / 127.0f) * (clip_max[1] / 127.0f);
    #pragma unroll
    for (int mi = 0; mi < 4; ++mi) {
        const int row0 = brow + wm * 64 + mi * 16 + lk * 4;
        #pragma unroll
        for (int ni = 0; ni < 4; ++ni) {
            const int col = bcol + wn * 64 + ni * 16 + lr;
            const float bv = bias[col];
            #pragma unroll
            for (int j = 0; j < 4; ++j)
                C[(size_t)(row0 + j) * N_ + col] = acc[mi][ni][j] * s + bv;
        }
    }
}

extern "C" void kernel_launch(void* const* d_in, const int* in_sizes, int n_in,
                              void* d_out, int out_size, void* d_ws, size_t ws_size,
                              hipStream_t stream) {
    const float* x    = (const float*)d_in[0];   // [8,2048,4096] fp32
    const float* w    = (const float*)d_in[1];   // [4096,4096] fp32
    const float* bias = (const float*)d_in[2];   // [4096] fp32
    const float* cm   = (const float*)d_in[3];   // [3] fp32
    float* out = (float*)d_out;                  // [8,2048,4096] fp32

    ushort* qx = (ushort*)d_ws;                  // M_*K_ bf16 = 128 MiB
    ushort* qw = qx + (size_t)M_ * K_;           // N_*K_ bf16 = 32 MiB

    quant_to_bf16<<<2048, 256, 0, stream>>>(x, qx, cm, 0, (M_ * (long long)K_) / 8);
    quant_to_bf16<<<1024, 256, 0, stream>>>(w, qw, cm, 1, (N_ * (long long)K_) / 8);

    const int grid = (M_ / BM) * (N_ / BN);      // 128 * 32 = 4096
    gemm_qbf16<<<grid, 256, 0, stream>>>(qx, qw, bias, cm, out);
}

// Round 3
// 892.862 us; speedup vs baseline: 1.2980x; 1.2980x over previous
//
#include <hip/hip_runtime.h>
#include <hip/hip_bf16.h>

typedef short s16x8 __attribute__((ext_vector_type(8)));
typedef float f32x4 __attribute__((ext_vector_type(4)));

constexpr int M_ = 16384;   // 8 * 2048
constexpr int N_ = 4096;    // d_out
constexpr int K_ = 4096;    // d_in
constexpr int BM = 256, BN = 256, BK = 64;
constexpr int NKT = K_ / BK;   // 64 K-tiles

// ---------------------------------------------------------------------------
// Quantize fp32 -> integer-valued bf16 (q = rint(clip(x,-c,c)/(c/127)))
// ---------------------------------------------------------------------------
__global__ __launch_bounds__(256) void quant_to_bf16(
    const float* __restrict__ in, ushort* __restrict__ out,
    const float* __restrict__ clip_max, int cm_idx, int n8)
{
    const float c = clip_max[cm_idx];
    const float scale = c / 127.0f;
    int i = blockIdx.x * blockDim.x + threadIdx.x;
    const int stride = gridDim.x * blockDim.x;
    for (; i < n8; i += stride) {
        float4 v0 = ((const float4*)in)[2 * i];
        float4 v1 = ((const float4*)in)[2 * i + 1];
        float t[8] = {v0.x, v0.y, v0.z, v0.w, v1.x, v1.y, v1.z, v1.w};
        union { s16x8 v; __hip_bfloat16 h[8]; } u;
        #pragma unroll
        for (int j = 0; j < 8; ++j) {
            float xc = fminf(fmaxf(t[j], -c), c);
            float q  = rintf(xc / scale);     // round-half-even == jnp.round
            u.h[j] = __float2bfloat16(q);     // exact (|q| <= 127)
        }
        ((s16x8*)out)[i] = u.v;
    }
}

// ---------------------------------------------------------------------------
// 256x256 8-phase bf16 GEMM (m201 template), both operands K-major:
//   C[m][n] = (sum_k A[m][k]*B[n][k]) * s + bias[n]
// 8 waves (2M x 4N), BK=64, LDS 128 KiB double-buffered, XOR-swizzled
// (chunk ^= row&7, 16B granules), counted vmcnt(4) at phases 4/8 only.
// ---------------------------------------------------------------------------
__global__ __launch_bounds__(512, 2) void gemm_qbf16_8ph(
    const ushort* __restrict__ A, const ushort* __restrict__ B,
    const float* __restrict__ bias, const float* __restrict__ clip_max,
    float* __restrict__ C)
{
    // 128 KiB: As0 | Bs0 | As1 | Bs1, 32 KiB each ([256 rows][64 bf16] = 128 B/row)
    __shared__ __align__(16) ushort smem[65536];
    char* sb = (char*)smem;
    constexpr int AS0 = 0, BS0 = 32768, AS1 = 65536, BS1 = 98304;

    const int tid  = threadIdx.x;
    const int lane = tid & 63;
    const int wid  = tid >> 6;
    const int wm   = wid >> 2;         // 0..1 -> 128-row band
    const int wn   = wid & 3;          // 0..3 -> 64-col band

    // XCD-aware bijective swizzle (grid = 1024, %8==0)
    const int bid = blockIdx.x;
    const int swz = (bid & 7) * (gridDim.x >> 3) + (bid >> 3);
    const int nt  = swz & (N_ / BN - 1);   // 16 n-tiles, fastest (A-panel L2 reuse)
    const int mt  = swz >> 4;
    const int m0  = mt * BM, n0 = nt * BN;

    // Staging: thread t writes LDS linearly (row = t>>3, chunk = t&7, 16B granules).
    // Pre-swizzle the GLOBAL source so LDS[d] holds logical chunk (d_chunk ^ row&7).
    const size_t st_off = (size_t)(tid >> 3) * K_
                        + (size_t)((((tid & 7) ^ ((tid >> 3) & 7)) & 7) << 3);
    // Read side: logical chunk (ks*4 + lane>>4) lives at LDS chunk ^ (row&7), row&7 == lane&7.
    const int rd0 = (lane & 15) * 128 + ((((lane >> 4) ^ (lane & 7)) & 7) << 4);
    const int rd1 = rd0 ^ 64;          // ks=1 flips chunk bit 2 (byte bit 6)

    #define GLOAD(SRC, LDSOFF) \
        __builtin_amdgcn_global_load_lds( \
            (const __attribute__((address_space(1))) void*)(SRC), \
            (__attribute__((address_space(3))) void*)(sb + (LDSOFF)), 16, 0, 0)

    // Stage one 128-row half-tile (16 KiB = 2 rounds of 512 thr x 16 B)
    #define STAGE_A(BUFB, H, KT) { \
        const ushort* s_ = A + (size_t)(m0 + (H)*128) * K_ + (size_t)(KT)*64 + st_off; \
        GLOAD(s_,                  (BUFB) + (H)*16384 + tid*16); \
        GLOAD(s_ + (size_t)64*K_,  (BUFB) + (H)*16384 + 8192 + tid*16); }
    #define STAGE_B(BUFB, H, KT) { \
        const ushort* s_ = B + (size_t)(n0 + (H)*128) * K_ + (size_t)(KT)*64 + st_off; \
        GLOAD(s_,                  (BUFB) + (H)*16384 + tid*16); \
        GLOAD(s_ + (size_t)64*K_,  (BUFB) + (H)*16384 + 8192 + tid*16); }

    s16x8 alo[4][2], ahi[4][2], bfr[2][2];
    f32x4 acc[8][4] = {};   // [mh*4+f][nh*2+g], all statically indexed

    #define RD_A(DST, BUFB, MH) { \
        const char* p_ = sb + (BUFB) + wm*16384 + (MH)*8192; \
        _Pragma("unroll") for (int f = 0; f < 4; ++f) { \
            DST[f][0] = *(const s16x8*)(p_ + f*2048 + rd0); \
            DST[f][1] = *(const s16x8*)(p_ + f*2048 + rd1); } }
    #define RD_B(BUFB, NH) { \
        const char* p_ = sb + (BUFB) + wn*8192 + (NH)*4096; \
        _Pragma("unroll") for (int g = 0; g < 2; ++g) { \
            bfr[g][0] = *(const s16x8*)(p_ + g*2048 + rd0); \
            bfr[g][1] = *(const s16x8*)(p_ + g*2048 + rd1); } }

    #define MFMA_Q(ASET, MBASE, NH) { \
        __builtin_amdgcn_s_setprio(1); \
        _Pragma("unroll") for (int f = 0; f < 4; ++f) \
        _Pragma("unroll") for (int g = 0; g < 2; ++g) \
        _Pragma("unroll") for (int ks = 0; ks < 2; ++ks) \
            acc[(MBASE)+f][(NH)*2+g] = __builtin_amdgcn_mfma_f32_16x16x32_bf16( \
                ASET[f][ks], bfr[g][ks], acc[(MBASE)+f][(NH)*2+g], 0, 0, 0); \
        __builtin_amdgcn_s_setprio(0); }

    #define BAR()   __builtin_amdgcn_s_barrier()
    #define LGKM0() asm volatile("s_waitcnt lgkmcnt(0)" ::: "memory")
    #define VM4()   asm volatile("s_waitcnt vmcnt(4)" ::: "memory")

    // 4 phases of one K-tile. Quadrant order (mh,nh): (0,0),(1,0),(0,1),(1,1).
    // A kept as two reg sets (alo/ahi) so LDS A-halves die after p1; B reloaded at p2.
    #define KTILE(ABUF, BBUF, S0, S1, S2, S3) \
        RD_A(alo, ABUF, 0); RD_B(BBUF, 0); S0; BAR(); LGKM0(); MFMA_Q(alo, 0, 0); BAR(); \
        RD_A(ahi, ABUF, 1); S1;            BAR(); LGKM0(); MFMA_Q(ahi, 4, 0); BAR(); \
        RD_B(BBUF, 1); S2;                 BAR(); LGKM0(); MFMA_Q(alo, 0, 1); BAR(); \
        S3;                                BAR();          MFMA_Q(ahi, 4, 1); VM4(); BAR();

    // Prologue: tile0 -> buf0 (4 halves), tile1 A -> buf1 (2 halves); wait tile0.
    STAGE_A(AS0, 0, 0); STAGE_A(AS0, 1, 0); STAGE_B(BS0, 0, 0); STAGE_B(BS0, 1, 0);
    STAGE_A(AS1, 0, 1); STAGE_A(AS1, 1, 1);
    VM4(); BAR();

    // Steady state: stage schedule p0..p7 =
    //   b1.B0<-kt1, b1.B1<-kt1, b0.A0<-kt+2, b0.A1<-kt+2,
    //   b0.B0<-kt+2, b0.B1<-kt+2, b1.A0<-kt+3, b1.A1<-kt+3
    // Each stage target is dead >=2 phases; vmcnt(4) at p3/p7 retires exactly the
    // 4 half-tiles (8 loads) needed by the next 4 phases. Tail stages wrap (&63).
    for (int i = 0; i < NKT / 2; ++i) {
        const int kt1 = 2 * i + 1;
        const int ktA = (2 * i + 2) & (NKT - 1);
        const int ktB = (2 * i + 3) & (NKT - 1);
        KTILE(AS0, BS0,
              STAGE_B(BS1, 0, kt1), STAGE_B(BS1, 1, kt1),
              STAGE_A(AS0, 0, ktA), STAGE_A(AS0, 1, ktA))
        KTILE(AS1, BS1,
              STAGE_B(BS0, 0, ktA), STAGE_B(BS0, 1, ktA),
              STAGE_A(AS1, 0, ktB), STAGE_A(AS1, 1, ktB))
    }

    // Epilogue: scale + bias (C/D layout: col = lane&15, row = (lane>>4)*4 + j)
    const float s = (clip_max[0] / 127.0f) * (clip_max[1] / 127.0f);
    const int l15 = lane & 15, l4 = lane >> 4;
    #pragma unroll
    for (int mh = 0; mh < 2; ++mh)
    #pragma unroll
    for (int f = 0; f < 4; ++f) {
        const int row0 = m0 + wm * 128 + mh * 64 + f * 16 + l4 * 4;
        #pragma unroll
        for (int nh = 0; nh < 2; ++nh)
        #pragma unroll
        for (int g = 0; g < 2; ++g) {
            const int col = n0 + wn * 64 + nh * 32 + g * 16 + l15;
            const float bv = bias[col];
            f32x4 v = acc[mh * 4 + f][nh * 2 + g];
            #pragma unroll
            for (int j = 0; j < 4; ++j)
                C[(size_t)(row0 + j) * N_ + col] = v[j] * s + bv;
        }
    }
}

extern "C" void kernel_launch(void* const* d_in, const int* in_sizes, int n_in,
                              void* d_out, int out_size, void* d_ws, size_t ws_size,
                              hipStream_t stream) {
    const float* x    = (const float*)d_in[0];   // [8,2048,4096] fp32
    const float* w    = (const float*)d_in[1];   // [4096,4096] fp32
    const float* bias = (const float*)d_in[2];   // [4096] fp32
    const float* cm   = (const float*)d_in[3];   // [3] fp32
    float* out = (float*)d_out;                  // [8,2048,4096] fp32

    ushort* qx = (ushort*)d_ws;                  // M_*K_ bf16 = 128 MiB
    ushort* qw = qx + (size_t)M_ * K_;           // N_*K_ bf16 = 32 MiB

    quant_to_bf16<<<2048, 256, 0, stream>>>(x, qx, cm, 0, (M_ * (long long)K_) / 8);
    quant_to_bf16<<<1024, 256, 0, stream>>>(w, qw, cm, 1, (N_ * (long long)K_) / 8);

    const int grid = (M_ / BM) * (N_ / BN);      // 64 * 16 = 1024
    gemm_qbf16_8ph<<<grid, 512, 0, stream>>>(qx, qw, bias, cm, out);
}